// Round 1
// baseline (262.157 us; speedup 1.0000x reference)
//
#include <hip/hip_runtime.h>
#include <hip/hip_bf16.h>
#include <cstdint>

#define TSEQ 2048
#define NB   2
#define NH   16
#define NKV  4
#define HD   128
#define EMB  2048
#define WIN  512

typedef unsigned short u16;
typedef __attribute__((ext_vector_type(8))) short s16x8;
typedef __attribute__((ext_vector_type(4))) float f32x4;
typedef __attribute__((ext_vector_type(16))) float f32x16;
typedef __attribute__((ext_vector_type(4))) unsigned short u16x4;
typedef __attribute__((ext_vector_type(8))) unsigned short u16x8;

__device__ __forceinline__ u16 f2bf(float x) {
    unsigned u = __builtin_bit_cast(unsigned, x);
    u += 0x7fffu + ((u >> 16) & 1u);
    return (u16)(u >> 16);
}
__device__ __forceinline__ float bf2f(u16 u) {
    return __builtin_bit_cast(float, ((unsigned)u) << 16);
}
__device__ __forceinline__ float ex2(float x) {
    return __builtin_amdgcn_exp2f(x);
}

__device__ __forceinline__ void gld_lds16(const void* g, void* l) {
    __builtin_amdgcn_global_load_lds(
        (__attribute__((address_space(1))) void*)(void*)(g),
        (__attribute__((address_space(3))) void*)(l),
        16, 0, 0);
}

__device__ __forceinline__ f32x4 mfma16(s16x8 a, s16x8 b, f32x4 c) {
    return __builtin_amdgcn_mfma_f32_16x16x32_bf16(a, b, c, 0, 0, 0);
}
__device__ __forceinline__ f32x16 mfma32(s16x8 a, s16x8 b, f32x16 c) {
    return __builtin_amdgcn_mfma_f32_32x32x16_bf16(a, b, c, 0, 0, 0);
}

// ---- DPP 16-lane reductions ----
template <int CTRL>
__device__ __forceinline__ float dpp_movf(float x) {
    return __builtin_bit_cast(float,
        __builtin_amdgcn_update_dpp(0, __builtin_bit_cast(int, x), CTRL, 0xF, 0xF, true));
}
__device__ __forceinline__ float dpp_max16(float x) {
    x = fmaxf(x, dpp_movf<0xB1>(x));
    x = fmaxf(x, dpp_movf<0x4E>(x));
    x = fmaxf(x, dpp_movf<0x128>(x));
    x = fmaxf(x, dpp_movf<0x124>(x));
    return x;
}
__device__ __forceinline__ float dpp_sum16(float x) {
    x += dpp_movf<0xB1>(x);
    x += dpp_movf<0x4E>(x);
    x += dpp_movf<0x128>(x);
    x += dpp_movf<0x124>(x);
    return x;
}

// ---------------- fused fp32 -> bf16 casts + rope table ----------------
__global__ void cast_all(const float* __restrict__ x,  const float* __restrict__ wq,
                         const float* __restrict__ wk, const float* __restrict__ wv,
                         const float* __restrict__ wo,
                         u16* __restrict__ xb, u16* __restrict__ wqb,
                         u16* __restrict__ wkvb, u16* __restrict__ wob,
                         float* __restrict__ tab) {
    if (blockIdx.x >= 18432) {
        int i = (blockIdx.x - 18432) * 256 + threadIdx.x;   // 131072 threads
        int t = i >> 6, d = i & 63;
        float inv = __expf(-(float)d * (9.210340371976184f / 64.0f));
        float s, c;
        sincosf((float)t * inv, &s, &c);
        tab[i] = c;
        tab[131072 + i] = s;
        return;
    }
    long i = ((long)blockIdx.x * 256 + threadIdx.x) * 4;
    const float* s; u16* d; long off;
    if (i < 8388608L)        { s = x;  d = xb;             off = i; }
    else if (i < 12582912L)  { s = wq; d = wqb;            off = i - 8388608L; }
    else if (i < 13631488L)  { s = wk; d = wkvb;           off = i - 12582912L; }
    else if (i < 14680064L)  { s = wv; d = wkvb + 1048576; off = i - 13631488L; }
    else                     { s = wo; d = wob;            off = i - 14680064L; }
    float4 v = *(const float4*)(s + off);
    u16x4 o;
    o[0] = f2bf(v.x); o[1] = f2bf(v.y); o[2] = f2bf(v.z); o[3] = f2bf(v.w);
    *(u16x4*)(d + off) = o;
}

// ---------------- 256-wide 8-wave phase-split GEMM, counted vmcnt ----------------
// C[M][N] = A[M][K] * B[N][K]^T, bf16 in, 32x32x16 MFMA, BK=64.
// BM=256 always. MODE 3: BN=256 (QKV fused, grid 12x16); MODE 0: BN=128 (fp32 out,
// grid 16x16 = full CU round). 512 threads = 8 waves; MODE3 wave grid 2Mx4N
// (per-wave 128x64, acc[4][2]); MODE0 wave grid 4Mx2N (per-wave 64x64, acc[2][2]).
// LDS double-buffered (128 KB / 96 KB). Chunk-XOR swizzle sig(row)=((row>>1)^(row>>2))&7
// on the GLOBAL source side of global_load_lds (proven conflict-free in prior kernel).
// Schedule per K-tile: 4 (or 2) phases {ds_read frags; s_barrier; setprio1; mfma x8;
// setprio0; s_barrier}. Tile t+2 is staged into the buffer read this iteration, but
// only into regions whose reads completed at an earlier phase barrier (A-half after
// phase 1, remainder after last phase). Top-of-iteration wait is a counted vmcnt
// (8 for MODE3, 6 for MODE0) -- never 0 in the steady state -- so the next tile's
// loads stay in flight across all barriers (T3+T4), with setprio (T5).
#define RDFRAG(base, offb, sg, ks) \
    (*(const s16x8*)((base) + (offb) + ((((half) + 2 * (ks)) ^ (sg)) << 4)))

template <int MODE>
__global__ __launch_bounds__(512) void gemm8(const u16* __restrict__ A, const u16* __restrict__ B,
                                             void* __restrict__ Cp, u16* __restrict__ vtp,
                                             u16* __restrict__ kp) {
    constexpr int BN     = (MODE == 3) ? 256 : 128;
    constexpr int NBB    = BN / 64;         // B stage-units
    constexpr int MT     = (MODE == 3) ? 4 : 2;
    constexpr int WM     = MT * 32;
    constexpr int K      = 2048;
    constexpr int NTK    = K / 64;
    constexpr int ABYTES = 32768;           // 256 x 64 bf16
    constexpr int BBYTES = BN * 128;
    constexpr int BUFB   = ABYTES + BBYTES;

    __shared__ __align__(16) char smem[2 * BUFB];

    const int tid  = threadIdx.x;
    const int lane = tid & 63;
    const int w    = tid >> 6;
    const int l31  = lane & 31;
    const int half = lane >> 5;
    const int wr   = (MODE == 3) ? (w >> 2) : (w >> 1);
    const int wc   = (MODE == 3) ? (w & 3) : (w & 1);
    const int bx   = blockIdx.x, by = blockIdx.y;

    // ---- staging: stage-unit s covers rows s*64 + w*8 + (lane>>3), chunk lane&7 ----
    const int srow   = w * 8 + (lane >> 3);
    const int schunk = lane & 7;
    const int sdoff  = w * 8 * 128;         // wave's byte offset inside a 64-row unit

    const u16* agp[4];
    const u16* bgp[NBB];
#pragma unroll
    for (int s = 0; s < 4; s++) {
        const int row = s * 64 + srow;
        const int sg  = ((row >> 1) ^ (row >> 2)) & 7;
        agp[s] = A + (size_t)(by * 256 + row) * K + ((schunk ^ sg) << 3);
    }
#pragma unroll
    for (int s = 0; s < NBB; s++) {
        const int row = s * 64 + srow;
        const int sg  = ((row >> 1) ^ (row >> 2)) & 7;
        bgp[s] = B + (size_t)(bx * BN + row) * K + ((schunk ^ sg) << 3);
    }

    // ---- loop-invariant fragment offsets ----
    int aoffb[MT], asg[MT];
#pragma unroll
    for (int mi = 0; mi < MT; mi++) {
        const int r = wr * WM + mi * 32 + l31;
        aoffb[mi] = r * 128;
        asg[mi]   = ((r >> 1) ^ (r >> 2)) & 7;
    }
    int boffb[2], bsg[2];
#pragma unroll
    for (int nj = 0; nj < 2; nj++) {
        const int r = wc * 64 + nj * 32 + l31;
        boffb[nj] = r * 128;
        bsg[nj]   = ((r >> 1) ^ (r >> 2)) & 7;
    }

    f32x16 acc[MT][2];
#pragma unroll
    for (int mi = 0; mi < MT; mi++)
#pragma unroll
        for (int nj = 0; nj < 2; nj++)
#pragma unroll
            for (int r = 0; r < 16; r++)
                acc[mi][nj][r] = 0.f;

    auto stage_a02 = [&](char* base) {
        gld_lds16(agp[0], base + sdoff);          agp[0] += 64;
        gld_lds16(agp[2], base + 16384 + sdoff);  agp[2] += 64;
    };
    auto stage_rest = [&](char* base) {
        gld_lds16(agp[1], base + 8192 + sdoff);   agp[1] += 64;
        gld_lds16(agp[3], base + 24576 + sdoff);  agp[3] += 64;
#pragma unroll
        for (int s = 0; s < NBB; s++) {
            gld_lds16(bgp[s], base + ABYTES + s * 8192 + sdoff);
            bgp[s] += 64;
        }
    };

    // ---- prologue: stage tiles 0 and 1 ----
    stage_a02(smem);        stage_rest(smem);
    stage_a02(smem + BUFB); stage_rest(smem + BUFB);

    for (int t = 0; t < NTK; ++t) {
        char* buf = smem + (t & 1) * BUFB;
        const char* Ab = buf;
        const char* Bb = buf + ABYTES;
        if (t < NTK - 1) {
            if constexpr (MODE == 3) asm volatile("s_waitcnt vmcnt(8)" ::: "memory");
            else                     asm volatile("s_waitcnt vmcnt(6)" ::: "memory");
        } else {
            asm volatile("s_waitcnt vmcnt(0)" ::: "memory");
        }
        __builtin_amdgcn_s_barrier();

        if constexpr (MODE == 3) {
            s16x8 aA[4], aB[4], bA[4], bB[4];
            // phase 0: read a(mi0), a(mi1), b(nj0); mfma (mi0,mi1) x nj0
#pragma unroll
            for (int ks = 0; ks < 4; ks++) {
                aA[ks] = RDFRAG(Ab, aoffb[0], asg[0], ks);
                aB[ks] = RDFRAG(Ab, aoffb[1], asg[1], ks);
                bA[ks] = RDFRAG(Bb, boffb[0], bsg[0], ks);
            }
            __builtin_amdgcn_s_barrier();
            __builtin_amdgcn_s_setprio(1);
#pragma unroll
            for (int ks = 0; ks < 4; ks++) {
                acc[0][0] = mfma32(aA[ks], bA[ks], acc[0][0]);
                acc[1][0] = mfma32(aB[ks], bA[ks], acc[1][0]);
            }
            __builtin_amdgcn_s_setprio(0);
            __builtin_amdgcn_s_barrier();
            // phase 1: read b(nj1); mfma (mi0,mi1) x nj1
#pragma unroll
            for (int ks = 0; ks < 4; ks++)
                bB[ks] = RDFRAG(Bb, boffb[1], bsg[1], ks);
            __builtin_amdgcn_s_barrier();
            __builtin_amdgcn_s_setprio(1);
#pragma unroll
            for (int ks = 0; ks < 4; ks++) {
                acc[0][1] = mfma32(aA[ks], bB[ks], acc[0][1]);
                acc[1][1] = mfma32(aB[ks], bB[ks], acc[1][1]);
            }
            __builtin_amdgcn_s_setprio(0);
            __builtin_amdgcn_s_barrier();
            // A rows [0,64)+[128,192) of this buffer are dead now -> stage t+2's half
            asm volatile("" ::: "memory");
            if (t + 2 < NTK) stage_a02(buf);
            // phase 2: read a(mi2), a(mi3); mfma (mi2,mi3) x nj1
#pragma unroll
            for (int ks = 0; ks < 4; ks++) {
                aA[ks] = RDFRAG(Ab, aoffb[2], asg[2], ks);
                aB[ks] = RDFRAG(Ab, aoffb[3], asg[3], ks);
            }
            __builtin_amdgcn_s_barrier();
            __builtin_amdgcn_s_setprio(1);
#pragma unroll
            for (int ks = 0; ks < 4; ks++) {
                acc[2][1] = mfma32(aA[ks], bB[ks], acc[2][1]);
                acc[3][1] = mfma32(aB[ks], bB[ks], acc[3][1]);
            }
            __builtin_amdgcn_s_setprio(0);
            __builtin_amdgcn_s_barrier();
            // phase 3: mfma (mi2,mi3) x nj0 (no new reads)
            __builtin_amdgcn_s_setprio(1);
#pragma unroll
            for (int ks = 0; ks < 4; ks++) {
                acc[2][0] = mfma32(aA[ks], bA[ks], acc[2][0]);
                acc[3][0] = mfma32(aB[ks], bA[ks], acc[3][0]);
            }
            __builtin_amdgcn_s_setprio(0);
            __builtin_amdgcn_s_barrier();
            asm volatile("" ::: "memory");
            if (t + 2 < NTK) stage_rest(buf);
        } else {
            s16x8 aA[4], aB[4], bA[4], bB[4];
            // phase 0: read a(mi0), b(nj0), b(nj1); mfma mi0 x (nj0,nj1)
#pragma unroll
            for (int ks = 0; ks < 4; ks++) {
                aA[ks] = RDFRAG(Ab, aoffb[0], asg[0], ks);
                bA[ks] = RDFRAG(Bb, boffb[0], bsg[0], ks);
                bB[ks] = RDFRAG(Bb, boffb[1], bsg[1], ks);
            }
            __builtin_amdgcn_s_barrier();
            __builtin_amdgcn_s_setprio(1);
#pragma unroll
            for (int ks = 0; ks < 4; ks++) {
                acc[0][0] = mfma32(aA[ks], bA[ks], acc[0][0]);
                acc[0][1] = mfma32(aA[ks], bB[ks], acc[0][1]);
            }
            __builtin_amdgcn_s_setprio(0);
            __builtin_amdgcn_s_barrier();
            // phase 1: read a(mi1); mfma mi1 x (nj0,nj1)
#pragma unroll
            for (int ks = 0; ks < 4; ks++)
                aB[ks] = RDFRAG(Ab, aoffb[1], asg[1], ks);
            __builtin_amdgcn_s_barrier();
            __builtin_amdgcn_s_setprio(1);
#pragma unroll
            for (int ks = 0; ks < 4; ks++) {
                acc[1][0] = mfma32(aB[ks], bA[ks], acc[1][0]);
                acc[1][1] = mfma32(aB[ks], bB[ks], acc[1][1]);
            }
            __builtin_amdgcn_s_setprio(0);
            __builtin_amdgcn_s_barrier();
            asm volatile("" ::: "memory");
            if (t + 2 < NTK) { stage_a02(buf); stage_rest(buf); }
        }
    }

    // ---------------- epilogue ----------------
    const int row0 = by * 256 + wr * WM;
    if constexpr (MODE == 0) {
        const int col0 = bx * BN + wc * 64 + l31;
#pragma unroll
        for (int mi = 0; mi < MT; mi++)
#pragma unroll
            for (int nj = 0; nj < 2; nj++)
#pragma unroll
                for (int r = 0; r < 16; r++) {
                    const int crow = row0 + mi * 32 + (r & 3) + 8 * (r >> 2) + 4 * half;
                    ((float*)Cp)[(size_t)crow * 2048 + col0 + nj * 32] = acc[mi][nj][r];
                }
    } else {
        if (bx < 8) {
            const int col0 = bx * 256 + wc * 64 + l31;
#pragma unroll
            for (int mi = 0; mi < MT; mi++)
#pragma unroll
                for (int nj = 0; nj < 2; nj++)
#pragma unroll
                    for (int r = 0; r < 16; r++) {
                        const int crow = row0 + mi * 32 + (r & 3) + 8 * (r >> 2) + 4 * half;
                        ((u16*)Cp)[(size_t)crow * 2048 + col0 + nj * 32] = f2bf(acc[mi][nj][r]);
                    }
        } else if (bx < 10) {
            const int kcol0 = (bx - 8) * 256 + wc * 64 + l31;
#pragma unroll
            for (int mi = 0; mi < MT; mi++)
#pragma unroll
                for (int nj = 0; nj < 2; nj++)
#pragma unroll
                    for (int r = 0; r < 16; r++) {
                        const int crow = row0 + mi * 32 + (r & 3) + 8 * (r >> 2) + 4 * half;
                        kp[(size_t)crow * 512 + kcol0 + nj * 32] = f2bf(acc[mi][nj][r]);
                    }
        } else {
            // V: transpose through LDS (128 cols x 256 t, stride 264 u16),
            // write vt[b][kv][d][t] as 16B segments.
            const int bb = (by * 256) >> 11;
            const int t0 = (by * 256) & (TSEQ - 1);
            u16* tr = (u16*)smem;   // 128*264 u16 = 67584 B <= 2*BUFB
#pragma unroll
            for (int p = 0; p < 2; p++) {
                __syncthreads();
                if ((wc >> 1) == p) {
#pragma unroll
                    for (int mi = 0; mi < MT; mi++)
#pragma unroll
                        for (int nj = 0; nj < 2; nj++)
#pragma unroll
                            for (int r = 0; r < 16; r++) {
                                const int tl = wr * 128 + mi * 32 + (r & 3) + 8 * (r >> 2) + 4 * half;
                                const int cl = (wc & 1) * 64 + nj * 32 + l31;
                                tr[cl * 264 + tl] = f2bf(acc[mi][nj][r]);
                            }
                }
                __syncthreads();
#pragma unroll
                for (int s = 0; s < 8; s++) {
                    const int slot = s * 512 + tid;
                    const int dcol = slot >> 5;
                    const int tseg = slot & 31;
                    u16x8 val = *(const u16x8*)(tr + dcol * 264 + tseg * 8);
                    const int vcol = (bx - 10) * 256 + p * 128 + dcol;
                    *(u16x8*)(vtp + ((size_t)((bb * NKV + (vcol >> 7)) * HD + (vcol & 127))) * TSEQ +
                              t0 + tseg * 8) = val;
                }
            }
        }
    }
}

// ---------------- RoPE in-place on bf16 K via table ----------------
__global__ void rope_k(u16* __restrict__ buf, const float* __restrict__ tab) {
    int i = blockIdx.x * 256 + threadIdx.x;   // 1048576 threads
    int d   = i & 63;
    int hh  = (i >> 6) & 3;
    int row = i >> 8;
    int t   = row & (TSEQ - 1);
    size_t base = (size_t)row * 512 + hh * HD + d;
    float x1 = bf2f(buf[base]);
    float x2 = bf2f(buf[base + 64]);
    float c = tab[t * 64 + d];
    float s = tab[131072 + t * 64 + d];
    buf[base]      = f2bf(x1 * c - x2 * s);
    buf[base + 64] = f2bf(x2 * c + x1 * s);
}

// ---------------- flash attention: block = (b, kv, 16-q tile), 4 waves = 4 q-heads ----------------
__global__ __launch_bounds__(256, 3) void attn_kernel(const u16* __restrict__ qb, const u16* __restrict__ kb,
                                                      const u16* __restrict__ vt, const float* __restrict__ tab,
                                                      u16* __restrict__ ao) {
    __shared__ __align__(16) char smem[40960];
    u16* ks = (u16*)smem;              // 64 keys x 128 d  (16 KB), chunk-swizzled
    u16* vs = (u16*)(smem + 16384);    // 128 d x 64 keys (16 KB), chunk-swizzled
    u16* Pl = (u16*)(smem + 32768);    // 4 x 2 KB per-wave P tiles (16x64 bf16 each)

    const int tid  = threadIdx.x;
    const int w    = tid >> 6;
    const int lane = tid & 63;
    const int l15  = lane & 15;
    const int quad = lane >> 4;
    const int id   = blockIdx.x;
    const int kv   = id & 3;
    const int b    = (id >> 2) & 1;
    const int q0   = (id >> 3) * 16;
    const int h    = kv * 4 + w;
    u16* Pw = Pl + w * 1024;
    const float scale2 = 0.1275174089593282f;   // (1/sqrt(128)) * log2(e)

    const u16* kbase = kb + (size_t)b * TSEQ * 512 + kv * HD;
    const u16* vbase = vt + (size_t)(b * NKV + kv) * HD * TSEQ;

    // ---- Q fragments with fused RoPE from table ----
    s16x8 aq[4];
    {
        const u16* qrow = qb + (size_t)(b * TSEQ + q0 + l15) * EMB + h * HD + quad * 8;
        const float* ct = tab + (size_t)(q0 + l15) * 64 + quad * 8;
        float qf[4][8], cs[2][8], sn[2][8];
        *(float4*)(&cs[0][0]) = *(const float4*)(ct);
        *(float4*)(&cs[0][4]) = *(const float4*)(ct + 4);
        *(float4*)(&cs[1][0]) = *(const float4*)(ct + 32);
        *(float4*)(&cs[1][4]) = *(const float4*)(ct + 36);
        *(float4*)(&sn[0][0]) = *(const float4*)(ct + 131072);
        *(float4*)(&sn[0][4]) = *(const float4*)(ct + 131076);
        *(float4*)(&sn[1][0]) = *(const float4*)(ct + 131104);
        *(float4*)(&sn[1][4]) = *(const float4*)(ct + 131108);
#pragma unroll
        for (int c = 0; c < 4; c++)
#pragma unroll
            for (int e = 0; e < 8; e++)
                qf[c][e] = bf2f(qrow[c * 32 + e]);
#pragma unroll
        for (int c = 0; c < 2; c++)
#pragma unroll
            for (int e = 0; e < 8; e++) {
                float x1 = qf[c][e], x2 = qf[c + 2][e];
                qf[c][e]     = x1 * cs[c][e] - x2 * sn[c][e];
                qf[c + 2][e] = x2 * cs[c][e] + x1 * sn[c][e];
            }
#pragma unroll
        for (int c = 0; c < 4; c++)
#pragma unroll
            for (int e = 0; e < 8; e++)
                aq[c][e] = (short)f2bf(qf[c][e]);
    }

    f32x4 o[8];
#pragma unroll
    for (int n = 0; n < 8; n++) o[n] = f32x4{0.f, 0.f, 0.f, 0.f};
    float mrow[4] = {-1e30f, -1e30f, -1e30f, -1e30f};   // log2 domain
    float lrow[4] = {0.f, 0.f, 0.f, 0.f};

    int kb0 = q0 - (WIN - 1);
    if (kb0 < 0) kb0 = 0;
    kb0 &= ~63;

    for (int kbi = kb0; kbi <= q0 + 15; kbi += 64) {
        // ---- stage K (64x128) and V^T (128x64) into LDS, chunk-swizzled ----
#pragma unroll
        for (int s = 0; s < 4; s++) {
            int slot = s * 256 + tid;
            int i    = slot >> 4;
            int lc   = (slot & 15) ^ (i & 7);
            gld_lds16(kbase + (size_t)(kbi + i) * 512 + lc * 8, (char*)ks + slot * 16);
        }
#pragma unroll
        for (int s = 0; s < 4; s++) {
            int slot = s * 256 + tid;
            int d    = slot >> 3;
            int lc   = (slot & 7) ^ (d & 7);
            gld_lds16(vbase + (size_t)d * TSEQ + kbi + lc * 8, (char*)vs + slot * 16);
        }
        __syncthreads();

        // ---- QK^T from LDS ----
        f32x4 sv[4];
#pragma unroll
        for (int kt = 0; kt < 4; kt++) sv[kt] = f32x4{0.f, 0.f, 0.f, 0.f};
#pragma unroll
        for (int c = 0; c < 4; c++) {
            s16x8 bk[4];
#pragma unroll
            for (int kt = 0; kt < 4; kt++) {
                int sc = (c * 4 + quad) ^ (l15 & 7);
                bk[kt] = *(const s16x8*)(ks + (kt * 16 + l15) * 128 + sc * 8);
            }
#pragma unroll
            for (int kt = 0; kt < 4; kt++)
                sv[kt] = mfma16(aq[c], bk[kt], sv[kt]);
        }

        // ---- online softmax in exp2 domain ----
        const bool full = (kbi >= q0 - 496) && (kbi + 63 <= q0);  // block-uniform
        float alpha[4], p[4][4];
#pragma unroll
        for (int r = 0; r < 4; r++) {
            const int row = q0 + quad * 4 + r;
            float v[4];
            if (full) {
#pragma unroll
                for (int kt = 0; kt < 4; kt++) v[kt] = sv[kt][r] * scale2;
            } else {
#pragma unroll
                for (int kt = 0; kt < 4; kt++) {
                    int cidx = kbi + kt * 16 + l15;
                    v[kt] = (cidx <= row && row - cidx < WIN) ? sv[kt][r] * scale2 : -1e30f;
                }
            }
            float mx = fmaxf(fmaxf(v[0], v[1]), fmaxf(v[2], v[3]));
            mx = dpp_max16(mx);
            float mnew = fmaxf(mrow[r], mx);
            alpha[r] = ex2(mrow[r] - mnew);
            float e0 = ex2(v[0] - mnew);
            float e1 = ex2(v[1] - mnew);
            float e2 = ex2(v[2] - mnew);
            float e3 = ex2(v[3] - mnew);
            float rs = (e0 + e1) + (e2 + e3);
            rs = dpp_sum16(rs);
            lrow[r] = lrow[r] * alpha[r] + rs;
            mrow[r] = mnew;
            p[0][r] = e0; p[1][r] = e1; p[2][r] = e2; p[3][r] = e3;
        }
#pragma unroll
        for (int n = 0; n < 8; n++) {
            o[n][0] *= alpha[0]; o[n][1] *= alpha[1];
            o[n][2] *= alpha[2]; o[n][3] *= alpha[3];
        }

        // ---- P: C-layout -> LDS -> A-layout (per-wave private 2KB region) ----
#pragma unroll
        for (int r = 0; r < 4; r++)
#pragma unroll
            for (int kt = 0; kt < 4; kt++)
                Pw[(kt >> 1) * 512 + (quad * 4 + r) * 32 + (kt & 1) * 16 + l15] = f2bf(p[kt][r]);
        asm volatile("s_waitcnt lgkmcnt(0)" ::: "memory");
        s16x8 ap0 = *(const s16x8*)(Pw + l15 * 32 + quad * 8);
        s16x8 ap1 = *(const s16x8*)(Pw + 512 + l15 * 32 + quad * 8);

        // ---- PV from LDS V^T ----
#pragma unroll
        for (int n = 0; n < 8; n++) {
            int sc = quad ^ (l15 & 7);
            s16x8 bv = *(const s16x8*)(vs + (n * 16 + l15) * 64 + sc * 8);
            o[n] = mfma16(ap0, bv, o[n]);
        }
#pragma unroll
        for (int n = 0; n < 8; n++) {
            int sc = (4 + quad) ^ (l15 & 7);
            s16x8 bv = *(const s16x8*)(vs + (n * 16 + l15) * 64 + sc * 8);
            o[n] = mfma16(ap1, bv, o[n]);
        }
        __syncthreads();
    }

    // ---- epilogue: LDS transpose (stride 136 -> aligned b128) -> coalesced stores ----
    float linv[4];
#pragma unroll
    for (int r = 0; r < 4; r++) linv[r] = 1.0f / lrow[r];
    u16* Ow = (u16*)(smem + w * 4352);   // 16 x 136 u16 = 4352 B, per-wave
#pragma unroll
    for (int n = 0; n < 8; n++)
#pragma unroll
        for (int r = 0; r < 4; r++)
            Ow[(quad * 4 + r) * 136 + n * 16 + l15] = f2bf(o[n][r] * linv[r]);
    asm volatile("s_waitcnt lgkmcnt(0)" ::: "memory");
#pragma unroll
    for (int s = 0; s < 4; s++) {
        int row = s * 4 + quad;
        u16x8 val = *(const u16x8*)(Ow + row * 136 + l15 * 8);
        *(u16x8*)(ao + (size_t)(b * TSEQ + q0 + row) * EMB + h * HD + l15 * 8) = val;
    }
}

extern "C" void kernel_launch(void* const* d_in, const int* in_sizes, int n_in,
                              void* d_out, int out_size, void* d_ws, size_t ws_size,
                              hipStream_t stream) {
    const float* x  = (const float*)d_in[0];
    const float* Wq = (const float*)d_in[1];
    const float* Wk = (const float*)d_in[2];
    const float* Wv = (const float*)d_in[3];
    const float* Wo = (const float*)d_in[4];
    float* out = (float*)d_out;

    u16* ws   = (u16*)d_ws;
    u16* xb   = ws;                 //  8388608  (4096 x 2048)  [reused as ao]
    u16* wqb  = ws + 8388608L;      //  4194304  } adjacent: Wq|Wk|Wv = 3072 x 2048
    u16* wkvb = ws + 12582912L;     //  2097152  }
    u16* wob  = ws + 14680064L;     //  4194304
    u16* qb   = ws + 18874368L;     //  8388608  raw Q (rope fused in attn)
    u16* kbuf = ws + 27262976L;     //  2097152  (4096 x 512) roped K
    u16* vt   = ws + 29360128L;     //  2097152  (b,kv,d,t)
    float* tab = (float*)(ws + 31457280L);  // 262144 floats = 1 MB (cos|sin)
    u16* ao   = xb;
    // total ws < 64 MB

    cast_all<<<18944, 256, 0, stream>>>(x, Wq, Wk, Wv, Wo, xb, wqb, wkvb, wob, tab);

    // fused QKV projection: B = [Wq|Wk|Wv] (3072 x 2048), 256x256 tiles
    gemm8<3><<<dim3(12, 16), 512, 0, stream>>>(xb, wqb, qb, vt, kbuf);

    rope_k<<<4096, 256, 0, stream>>>(kbuf, tab);

    attn_kernel<<<1024, 256, 0, stream>>>(qb, kbuf, vt, tab, ao);

    // output projection: 256x128 tiles -> 16x16 = 256 blocks = one full CU round
    gemm8<0><<<dim3(16, 16), 512, 0, stream>>>(ao, wob, out, nullptr, nullptr);
}

// Round 2
// 253.192 us; speedup vs baseline: 1.0354x; 1.0354x over previous
//
#include <hip/hip_runtime.h>
#include <hip/hip_bf16.h>
#include <cstdint>

#define TSEQ 2048
#define NB   2
#define NH   16
#define NKV  4
#define HD   128
#define EMB  2048
#define WIN  512

typedef unsigned short u16;
typedef __attribute__((ext_vector_type(8))) short s16x8;
typedef __attribute__((ext_vector_type(4))) float f32x4;
typedef __attribute__((ext_vector_type(16))) float f32x16;
typedef __attribute__((ext_vector_type(4))) unsigned short u16x4;
typedef __attribute__((ext_vector_type(8))) unsigned short u16x8;

__device__ __forceinline__ u16 f2bf(float x) {
    unsigned u = __builtin_bit_cast(unsigned, x);
    u += 0x7fffu + ((u >> 16) & 1u);
    return (u16)(u >> 16);
}
__device__ __forceinline__ float bf2f(u16 u) {
    return __builtin_bit_cast(float, ((unsigned)u) << 16);
}
__device__ __forceinline__ float ex2(float x) {
    return __builtin_amdgcn_exp2f(x);
}

__device__ __forceinline__ void gld_lds16(const void* g, void* l) {
    __builtin_amdgcn_global_load_lds(
        (__attribute__((address_space(1))) void*)(void*)(g),
        (__attribute__((address_space(3))) void*)(l),
        16, 0, 0);
}

__device__ __forceinline__ f32x4 mfma16(s16x8 a, s16x8 b, f32x4 c) {
    return __builtin_amdgcn_mfma_f32_16x16x32_bf16(a, b, c, 0, 0, 0);
}
__device__ __forceinline__ f32x16 mfma32(s16x8 a, s16x8 b, f32x16 c) {
    return __builtin_amdgcn_mfma_f32_32x32x16_bf16(a, b, c, 0, 0, 0);
}

// ---- DPP 16-lane reductions ----
template <int CTRL>
__device__ __forceinline__ float dpp_movf(float x) {
    return __builtin_bit_cast(float,
        __builtin_amdgcn_update_dpp(0, __builtin_bit_cast(int, x), CTRL, 0xF, 0xF, true));
}
__device__ __forceinline__ float dpp_max16(float x) {
    x = fmaxf(x, dpp_movf<0xB1>(x));
    x = fmaxf(x, dpp_movf<0x4E>(x));
    x = fmaxf(x, dpp_movf<0x128>(x));
    x = fmaxf(x, dpp_movf<0x124>(x));
    return x;
}
__device__ __forceinline__ float dpp_sum16(float x) {
    x += dpp_movf<0xB1>(x);
    x += dpp_movf<0x4E>(x);
    x += dpp_movf<0x128>(x);
    x += dpp_movf<0x124>(x);
    return x;
}

// ---------------- fused fp32 -> bf16 casts + rope table ----------------
__global__ void cast_all(const float* __restrict__ x,  const float* __restrict__ wq,
                         const float* __restrict__ wk, const float* __restrict__ wv,
                         const float* __restrict__ wo,
                         u16* __restrict__ xb, u16* __restrict__ wqb,
                         u16* __restrict__ wkvb, u16* __restrict__ wob,
                         float* __restrict__ tab) {
    if (blockIdx.x >= 18432) {
        int i = (blockIdx.x - 18432) * 256 + threadIdx.x;   // 131072 threads
        int t = i >> 6, d = i & 63;
        float inv = __expf(-(float)d * (9.210340371976184f / 64.0f));
        float s, c;
        sincosf((float)t * inv, &s, &c);
        tab[i] = c;
        tab[131072 + i] = s;
        return;
    }
    long i = ((long)blockIdx.x * 256 + threadIdx.x) * 4;
    const float* s; u16* d; long off;
    if (i < 8388608L)        { s = x;  d = xb;             off = i; }
    else if (i < 12582912L)  { s = wq; d = wqb;            off = i - 8388608L; }
    else if (i < 13631488L)  { s = wk; d = wkvb;           off = i - 12582912L; }
    else if (i < 14680064L)  { s = wv; d = wkvb + 1048576; off = i - 13631488L; }
    else                     { s = wo; d = wob;            off = i - 14680064L; }
    float4 v = *(const float4*)(s + off);
    u16x4 o;
    o[0] = f2bf(v.x); o[1] = f2bf(v.y); o[2] = f2bf(v.z); o[3] = f2bf(v.w);
    *(u16x4*)(d + off) = o;
}

// ---------------- 8-wave phase-split GEMM, counted vmcnt, FULL-GRID tiles ----------
// C[M][N] = A[M][K] * B[N][K]^T, bf16 in, 32x32x16 MFMA, BK=64, 512 threads = 8 waves.
// MODE 3 (QKV fused): BM=256 x BN=192 -> grid 16x16 = 256 blocks = one full CU round
//   (R1's 256x256 grid was 192 blocks: 64 CUs idle = the 25% loss).
// MODE 0 (Wo, fp32 out): BM=256 x BN=128 -> grid 16x16 = 256 blocks.
// Wave grid 4M x 2N, per-wave 64 x BN/2; acc[2][NT], NT = BN/64.
// Per K-tile: NT phases {ds_read frags; s_barrier; setprio1; 8 x mfma32; setprio0;
// s_barrier}. Each B fragment is consumed in exactly one phase (not kept live).
// A is fully read in phase 0 -> restage A for tile t+2 after phase 0; B after the
// last phase. Top-of-iteration wait is counted vmcnt(4+NT) -- never 0 in steady
// state (T3+T4) -- so next tile's loads stay in flight across all barriers.
// Chunk-XOR swizzle sig(row)=((row>>1)^(row>>2))&7 applied on the GLOBAL source of
// global_load_lds; LDS dest stays lane-contiguous (both-sides-or-neither rule).
#define RDFRAG(base, offb, sg, ks) \
    (*(const s16x8*)((base) + (offb) + ((((half) + 2 * (ks)) ^ (sg)) << 4)))

template <int MODE>
__global__ __launch_bounds__(512) void gemm8(const u16* __restrict__ A, const u16* __restrict__ B,
                                             void* __restrict__ Cp, u16* __restrict__ vtp,
                                             u16* __restrict__ kp) {
    constexpr int BN     = (MODE == 3) ? 192 : 128;
    constexpr int NBB    = BN / 64;         // B stage-units == MFMA col-tiles/wave
    constexpr int K      = 2048;
    constexpr int NTK    = K / 64;
    constexpr int ABYTES = 32768;           // 256 x 64 bf16
    constexpr int BBYTES = BN * 128;
    constexpr int BUFB   = ABYTES + BBYTES;
    constexpr int NLD    = 4 + NBB;         // loads per K-tile

    __shared__ __align__(16) char smem[2 * BUFB];

    const int tid  = threadIdx.x;
    const int lane = tid & 63;
    const int w    = tid >> 6;
    const int l31  = lane & 31;
    const int half = lane >> 5;
    const int wr   = w >> 1;                // 0..3 (M)
    const int wc   = w & 1;                 // 0..1 (N)
    const int bx   = blockIdx.x, by = blockIdx.y;

    // ---- staging: stage-unit s covers rows s*64 + w*8 + (lane>>3), chunk lane&7 ----
    const int srow   = w * 8 + (lane >> 3);
    const int schunk = lane & 7;
    const int sdoff  = w * 8 * 128;         // wave's byte offset inside a 64-row unit

    const u16* agp[4];
    const u16* bgp[NBB];
#pragma unroll
    for (int s = 0; s < 4; s++) {
        const int row = s * 64 + srow;
        const int sg  = ((row >> 1) ^ (row >> 2)) & 7;
        agp[s] = A + (size_t)(by * 256 + row) * K + ((schunk ^ sg) << 3);
    }
#pragma unroll
    for (int s = 0; s < NBB; s++) {
        const int row = s * 64 + srow;
        const int sg  = ((row >> 1) ^ (row >> 2)) & 7;
        bgp[s] = B + (size_t)(bx * BN + row) * K + ((schunk ^ sg) << 3);
    }

    // ---- loop-invariant fragment offsets ----
    int aoffb[2], asg[2];
#pragma unroll
    for (int mi = 0; mi < 2; mi++) {
        const int r = wr * 64 + mi * 32 + l31;
        aoffb[mi] = r * 128;
        asg[mi]   = ((r >> 1) ^ (r >> 2)) & 7;
    }
    int boffb[NBB], bsg[NBB];
#pragma unroll
    for (int nj = 0; nj < NBB; nj++) {
        const int r = wc * (BN / 2) + nj * 32 + l31;
        boffb[nj] = r * 128;
        bsg[nj]   = ((r >> 1) ^ (r >> 2)) & 7;
    }

    f32x16 acc[2][NBB];
#pragma unroll
    for (int mi = 0; mi < 2; mi++)
#pragma unroll
        for (int nj = 0; nj < NBB; nj++)
#pragma unroll
            for (int r = 0; r < 16; r++)
                acc[mi][nj][r] = 0.f;

    auto stage_A = [&](char* base) {
#pragma unroll
        for (int s = 0; s < 4; s++) {
            gld_lds16(agp[s], base + s * 8192 + sdoff);
            agp[s] += 64;
        }
    };
    auto stage_B = [&](char* base) {
#pragma unroll
        for (int s = 0; s < NBB; s++) {
            gld_lds16(bgp[s], base + ABYTES + s * 8192 + sdoff);
            bgp[s] += 64;
        }
    };

    // ---- prologue: stage tiles 0 and 1 ----
    stage_A(smem);        stage_B(smem);
    stage_A(smem + BUFB); stage_B(smem + BUFB);

    for (int t = 0; t < NTK; ++t) {
        char* buf = smem + (t & 1) * BUFB;
        const char* Ab = buf;
        const char* Bb = buf + ABYTES;
        // drain exactly tile t's loads (tile t+1's NLD stay in flight)
        if (t < NTK - 1) asm volatile("s_waitcnt vmcnt(%0)" :: "n"(NLD) : "memory");
        else             asm volatile("s_waitcnt vmcnt(0)" ::: "memory");
        __builtin_amdgcn_s_barrier();

        s16x8 a0[4], a1[4];
        {   // phase 0: read a(mi0), a(mi1), b(0); mfma (mi0,mi1) x 0
            s16x8 bf[4];
#pragma unroll
            for (int ks = 0; ks < 4; ks++) {
                a0[ks] = RDFRAG(Ab, aoffb[0], asg[0], ks);
                a1[ks] = RDFRAG(Ab, aoffb[1], asg[1], ks);
                bf[ks] = RDFRAG(Bb, boffb[0], bsg[0], ks);
            }
            __builtin_amdgcn_s_barrier();
            __builtin_amdgcn_s_setprio(1);
#pragma unroll
            for (int ks = 0; ks < 4; ks++) {
                acc[0][0] = mfma32(a0[ks], bf[ks], acc[0][0]);
                acc[1][0] = mfma32(a1[ks], bf[ks], acc[1][0]);
            }
            __builtin_amdgcn_s_setprio(0);
            __builtin_amdgcn_s_barrier();
        }
        // A fully read in phase 0 -> restage A region with tile t+2
        asm volatile("" ::: "memory");
        if (t + 2 < NTK) stage_A(buf);
#pragma unroll
        for (int j = 1; j < NBB; j++) {   // phases 1..NT-1: read b(j); mfma (mi0,mi1) x j
            s16x8 bf[4];
#pragma unroll
            for (int ks = 0; ks < 4; ks++)
                bf[ks] = RDFRAG(Bb, boffb[j], bsg[j], ks);
            __builtin_amdgcn_s_barrier();
            __builtin_amdgcn_s_setprio(1);
#pragma unroll
            for (int ks = 0; ks < 4; ks++) {
                acc[0][j] = mfma32(a0[ks], bf[ks], acc[0][j]);
                acc[1][j] = mfma32(a1[ks], bf[ks], acc[1][j]);
            }
            __builtin_amdgcn_s_setprio(0);
            __builtin_amdgcn_s_barrier();
        }
        asm volatile("" ::: "memory");
        if (t + 2 < NTK) stage_B(buf);
    }

    // ---------------- epilogue ----------------
    const int row0 = by * 256 + wr * 64;
    if constexpr (MODE == 0) {
        const int col0 = bx * 128 + wc * 64 + l31;
#pragma unroll
        for (int mi = 0; mi < 2; mi++)
#pragma unroll
            for (int nj = 0; nj < 2; nj++)
#pragma unroll
                for (int r = 0; r < 16; r++) {
                    const int crow = row0 + mi * 32 + (r & 3) + 8 * (r >> 2) + 4 * half;
                    ((float*)Cp)[(size_t)crow * 2048 + col0 + nj * 32] = acc[mi][nj][r];
                }
    } else {
        // per 32-col tile: cols [0,2048) -> Q, [2048,2560) -> K, [2560,3072) -> V
        // (boundaries are 32-aligned, so each tile has exactly one destination)
#pragma unroll
        for (int nj = 0; nj < NBB; nj++) {
            const int colbase = bx * 192 + wc * 96 + nj * 32;
            if (colbase >= 2560) continue;     // V handled below
            if (colbase < 2048) {
#pragma unroll
                for (int mi = 0; mi < 2; mi++)
#pragma unroll
                    for (int r = 0; r < 16; r++) {
                        const int crow = row0 + mi * 32 + (r & 3) + 8 * (r >> 2) + 4 * half;
                        ((u16*)Cp)[(size_t)crow * 2048 + colbase + l31] = f2bf(acc[mi][nj][r]);
                    }
            } else {
#pragma unroll
                for (int mi = 0; mi < 2; mi++)
#pragma unroll
                    for (int r = 0; r < 16; r++) {
                        const int crow = row0 + mi * 32 + (r & 3) + 8 * (r >> 2) + 4 * half;
                        kp[(size_t)crow * 512 + colbase - 2048 + l31] = f2bf(acc[mi][nj][r]);
                    }
            }
        }
        // V: per 32-col tile, transpose 32 d x 256 t through LDS (stride 264 u16,
        // 16B-aligned rows), write vt[b][kv][d][t] as contiguous 16B segments.
        const int bb = (by * 256) >> 11;
        const int t0 = (by * 256) & (TSEQ - 1);
        u16* tr = (u16*)smem;   // 32 x 264 u16 = 16896 B
#pragma unroll
        for (int wcx = 0; wcx < 2; wcx++)
#pragma unroll
            for (int njx = 0; njx < NBB; njx++) {
                const int colbase = bx * 192 + wcx * 96 + njx * 32;   // block-uniform
                if (colbase < 2560) continue;
                __syncthreads();
                if (wc == wcx) {
#pragma unroll
                    for (int mi = 0; mi < 2; mi++)
#pragma unroll
                        for (int r = 0; r < 16; r++) {
                            const int tl = wr * 64 + mi * 32 + (r & 3) + 8 * (r >> 2) + 4 * half;
                            tr[l31 * 264 + tl] = f2bf(acc[mi][njx][r]);
                        }
                }
                __syncthreads();
                const int voff = colbase - 2560;   // kv*128 + d-base
#pragma unroll
                for (int s = 0; s < 2; s++) {
                    const int slot = s * 512 + tid;
                    const int dl   = slot >> 5;
                    const int tseg = slot & 31;
                    u16x8 val = *(const u16x8*)(tr + dl * 264 + tseg * 8);
                    const int dg = voff + dl;
                    *(u16x8*)(vtp + ((size_t)((bb * NKV + (dg >> 7)) * HD + (dg & 127))) * TSEQ +
                              t0 + tseg * 8) = val;
                }
            }
    }
}

// ---------------- RoPE in-place on bf16 K via table ----------------
__global__ void rope_k(u16* __restrict__ buf, const float* __restrict__ tab) {
    int i = blockIdx.x * 256 + threadIdx.x;   // 1048576 threads
    int d   = i & 63;
    int hh  = (i >> 6) & 3;
    int row = i >> 8;
    int t   = row & (TSEQ - 1);
    size_t base = (size_t)row * 512 + hh * HD + d;
    float x1 = bf2f(buf[base]);
    float x2 = bf2f(buf[base + 64]);
    float c = tab[t * 64 + d];
    float s = tab[131072 + t * 64 + d];
    buf[base]      = f2bf(x1 * c - x2 * s);
    buf[base + 64] = f2bf(x2 * c + x1 * s);
}

// ---------------- flash attention: block = (b, kv, 16-q tile), 4 waves = 4 q-heads ----------------
__global__ __launch_bounds__(256, 3) void attn_kernel(const u16* __restrict__ qb, const u16* __restrict__ kb,
                                                      const u16* __restrict__ vt, const float* __restrict__ tab,
                                                      u16* __restrict__ ao) {
    __shared__ __align__(16) char smem[40960];
    u16* ks = (u16*)smem;              // 64 keys x 128 d  (16 KB), chunk-swizzled
    u16* vs = (u16*)(smem + 16384);    // 128 d x 64 keys (16 KB), chunk-swizzled
    u16* Pl = (u16*)(smem + 32768);    // 4 x 2 KB per-wave P tiles (16x64 bf16 each)

    const int tid  = threadIdx.x;
    const int w    = tid >> 6;
    const int lane = tid & 63;
    const int l15  = lane & 15;
    const int quad = lane >> 4;
    const int id   = blockIdx.x;
    const int kv   = id & 3;
    const int b    = (id >> 2) & 1;
    const int q0   = (id >> 3) * 16;
    const int h    = kv * 4 + w;
    u16* Pw = Pl + w * 1024;
    const float scale2 = 0.1275174089593282f;   // (1/sqrt(128)) * log2(e)

    const u16* kbase = kb + (size_t)b * TSEQ * 512 + kv * HD;
    const u16* vbase = vt + (size_t)(b * NKV + kv) * HD * TSEQ;

    // ---- Q fragments with fused RoPE from table ----
    s16x8 aq[4];
    {
        const u16* qrow = qb + (size_t)(b * TSEQ + q0 + l15) * EMB + h * HD + quad * 8;
        const float* ct = tab + (size_t)(q0 + l15) * 64 + quad * 8;
        float qf[4][8], cs[2][8], sn[2][8];
        *(float4*)(&cs[0][0]) = *(const float4*)(ct);
        *(float4*)(&cs[0][4]) = *(const float4*)(ct + 4);
        *(float4*)(&cs[1][0]) = *(const float4*)(ct + 32);
        *(float4*)(&cs[1][4]) = *(const float4*)(ct + 36);
        *(float4*)(&sn[0][0]) = *(const float4*)(ct + 131072);
        *(float4*)(&sn[0][4]) = *(const float4*)(ct + 131076);
        *(float4*)(&sn[1][0]) = *(const float4*)(ct + 131104);
        *(float4*)(&sn[1][4]) = *(const float4*)(ct + 131108);
#pragma unroll
        for (int c = 0; c < 4; c++)
#pragma unroll
            for (int e = 0; e < 8; e++)
                qf[c][e] = bf2f(qrow[c * 32 + e]);
#pragma unroll
        for (int c = 0; c < 2; c++)
#pragma unroll
            for (int e = 0; e < 8; e++) {
                float x1 = qf[c][e], x2 = qf[c + 2][e];
                qf[c][e]     = x1 * cs[c][e] - x2 * sn[c][e];
                qf[c + 2][e] = x2 * cs[c][e] + x1 * sn[c][e];
            }
#pragma unroll
        for (int c = 0; c < 4; c++)
#pragma unroll
            for (int e = 0; e < 8; e++)
                aq[c][e] = (short)f2bf(qf[c][e]);
    }

    f32x4 o[8];
#pragma unroll
    for (int n = 0; n < 8; n++) o[n] = f32x4{0.f, 0.f, 0.f, 0.f};
    float mrow[4] = {-1e30f, -1e30f, -1e30f, -1e30f};   // log2 domain
    float lrow[4] = {0.f, 0.f, 0.f, 0.f};

    int kb0 = q0 - (WIN - 1);
    if (kb0 < 0) kb0 = 0;
    kb0 &= ~63;

    for (int kbi = kb0; kbi <= q0 + 15; kbi += 64) {
        // ---- stage K (64x128) and V^T (128x64) into LDS, chunk-swizzled ----
#pragma unroll
        for (int s = 0; s < 4; s++) {
            int slot = s * 256 + tid;
            int i    = slot >> 4;
            int lc   = (slot & 15) ^ (i & 7);
            gld_lds16(kbase + (size_t)(kbi + i) * 512 + lc * 8, (char*)ks + slot * 16);
        }
#pragma unroll
        for (int s = 0; s < 4; s++) {
            int slot = s * 256 + tid;
            int d    = slot >> 3;
            int lc   = (slot & 7) ^ (d & 7);
            gld_lds16(vbase + (size_t)d * TSEQ + kbi + lc * 8, (char*)vs + slot * 16);
        }
        __syncthreads();

        // ---- QK^T from LDS ----
        f32x4 sv[4];
#pragma unroll
        for (int kt = 0; kt < 4; kt++) sv[kt] = f32x4{0.f, 0.f, 0.f, 0.f};
#pragma unroll
        for (int c = 0; c < 4; c++) {
            s16x8 bk[4];
#pragma unroll
            for (int kt = 0; kt < 4; kt++) {
                int sc = (c * 4 + quad) ^ (l15 & 7);
                bk[kt] = *(const s16x8*)(ks + (kt * 16 + l15) * 128 + sc * 8);
            }
#pragma unroll
            for (int kt = 0; kt < 4; kt++)
                sv[kt] = mfma16(aq[c], bk[kt], sv[kt]);
        }

        // ---- online softmax in exp2 domain ----
        const bool full = (kbi >= q0 - 496) && (kbi + 63 <= q0);  // block-uniform
        float alpha[4], p[4][4];
#pragma unroll
        for (int r = 0; r < 4; r++) {
            const int row = q0 + quad * 4 + r;
            float v[4];
            if (full) {
#pragma unroll
                for (int kt = 0; kt < 4; kt++) v[kt] = sv[kt][r] * scale2;
            } else {
#pragma unroll
                for (int kt = 0; kt < 4; kt++) {
                    int cidx = kbi + kt * 16 + l15;
                    v[kt] = (cidx <= row && row - cidx < WIN) ? sv[kt][r] * scale2 : -1e30f;
                }
            }
            float mx = fmaxf(fmaxf(v[0], v[1]), fmaxf(v[2], v[3]));
            mx = dpp_max16(mx);
            float mnew = fmaxf(mrow[r], mx);
            alpha[r] = ex2(mrow[r] - mnew);
            float e0 = ex2(v[0] - mnew);
            float e1 = ex2(v[1] - mnew);
            float e2 = ex2(v[2] - mnew);
            float e3 = ex2(v[3] - mnew);
            float rs = (e0 + e1) + (e2 + e3);
            rs = dpp_sum16(rs);
            lrow[r] = lrow[r] * alpha[r] + rs;
            mrow[r] = mnew;
            p[0][r] = e0; p[1][r] = e1; p[2][r] = e2; p[3][r] = e3;
        }
#pragma unroll
        for (int n = 0; n < 8; n++) {
            o[n][0] *= alpha[0]; o[n][1] *= alpha[1];
            o[n][2] *= alpha[2]; o[n][3] *= alpha[3];
        }

        // ---- P: C-layout -> LDS -> A-layout (per-wave private 2KB region) ----
#pragma unroll
        for (int r = 0; r < 4; r++)
#pragma unroll
            for (int kt = 0; kt < 4; kt++)
                Pw[(kt >> 1) * 512 + (quad * 4 + r) * 32 + (kt & 1) * 16 + l15] = f2bf(p[kt][r]);
        asm volatile("s_waitcnt lgkmcnt(0)" ::: "memory");
        s16x8 ap0 = *(const s16x8*)(Pw + l15 * 32 + quad * 8);
        s16x8 ap1 = *(const s16x8*)(Pw + 512 + l15 * 32 + quad * 8);

        // ---- PV from LDS V^T ----
#pragma unroll
        for (int n = 0; n < 8; n++) {
            int sc = quad ^ (l15 & 7);
            s16x8 bv = *(const s16x8*)(vs + (n * 16 + l15) * 64 + sc * 8);
            o[n] = mfma16(ap0, bv, o[n]);
        }
#pragma unroll
        for (int n = 0; n < 8; n++) {
            int sc = (4 + quad) ^ (l15 & 7);
            s16x8 bv = *(const s16x8*)(vs + (n * 16 + l15) * 64 + sc * 8);
            o[n] = mfma16(ap1, bv, o[n]);
        }
        __syncthreads();
    }

    // ---- epilogue: LDS transpose (stride 136 -> aligned b128) -> coalesced stores ----
    float linv[4];
#pragma unroll
    for (int r = 0; r < 4; r++) linv[r] = 1.0f / lrow[r];
    u16* Ow = (u16*)(smem + w * 4352);   // 16 x 136 u16 = 4352 B, per-wave
#pragma unroll
    for (int n = 0; n < 8; n++)
#pragma unroll
        for (int r = 0; r < 4; r++)
            Ow[(quad * 4 + r) * 136 + n * 16 + l15] = f2bf(o[n][r] * linv[r]);
    asm volatile("s_waitcnt lgkmcnt(0)" ::: "memory");
#pragma unroll
    for (int s = 0; s < 4; s++) {
        int row = s * 4 + quad;
        u16x8 val = *(const u16x8*)(Ow + row * 136 + l15 * 8);
        *(u16x8*)(ao + (size_t)(b * TSEQ + q0 + row) * EMB + h * HD + l15 * 8) = val;
    }
}

extern "C" void kernel_launch(void* const* d_in, const int* in_sizes, int n_in,
                              void* d_out, int out_size, void* d_ws, size_t ws_size,
                              hipStream_t stream) {
    const float* x  = (const float*)d_in[0];
    const float* Wq = (const float*)d_in[1];
    const float* Wk = (const float*)d_in[2];
    const float* Wv = (const float*)d_in[3];
    const float* Wo = (const float*)d_in[4];
    float* out = (float*)d_out;

    u16* ws   = (u16*)d_ws;
    u16* xb   = ws;                 //  8388608  (4096 x 2048)  [reused as ao]
    u16* wqb  = ws + 8388608L;      //  4194304  } adjacent: Wq|Wk|Wv = 3072 x 2048
    u16* wkvb = ws + 12582912L;     //  2097152  }
    u16* wob  = ws + 14680064L;     //  4194304
    u16* qb   = ws + 18874368L;     //  8388608  raw Q (rope fused in attn)
    u16* kbuf = ws + 27262976L;     //  2097152  (4096 x 512) roped K
    u16* vt   = ws + 29360128L;     //  2097152  (b,kv,d,t)
    float* tab = (float*)(ws + 31457280L);  // 262144 floats = 1 MB (cos|sin)
    u16* ao   = xb;
    // total ws < 64 MB

    cast_all<<<18944, 256, 0, stream>>>(x, Wq, Wk, Wv, Wo, xb, wqb, wkvb, wob, tab);

    // fused QKV projection: B = [Wq|Wk|Wv] (3072 x 2048), 256x192 tiles, full grid
    gemm8<3><<<dim3(16, 16), 512, 0, stream>>>(xb, wqb, qb, vt, kbuf);

    rope_k<<<4096, 256, 0, stream>>>(kbuf, tab);

    attn_kernel<<<1024, 256, 0, stream>>>(qb, kbuf, vt, tab, ao);

    // output projection: 256x128 tiles -> 16x16 = 256 blocks = one full CU round
    gemm8<0><<<dim3(16, 16), 512, 0, stream>>>(ao, wob, out, nullptr, nullptr);
}